// Round 1
// baseline (69.180 us; speedup 1.0000x reference)
//
#include <hip/hip_runtime.h>

// Problem constants (from reference):
// X:[B,T,I] f32, ind:[B,E,K] int, W:[E,I,J] f32 -> Y:[B,E,K,J] f32
// Y[b,e,k,j] = sum_i X[b, ind[b,e,k], i] * W[e,i,j]
#define B_ 8
#define T_ 8192
#define I_ 128
#define E_ 16
#define J_ 128
#define K_ 1024
#define KT 32            // k-rows per block

// Block: 256 threads. LDS: W[e] full (128x128 f32 = 64KB) + 32 gathered X rows
// (32x128 f32 = 16KB) = 80KB exactly -> 2 blocks/CU (160KB LDS), 8 waves/CU.
__global__ __launch_bounds__(256, 2)
void gather_gemm_f32(const float* __restrict__ X,
                     const int* __restrict__ ind,
                     const float* __restrict__ W,
                     float* __restrict__ Y) {
    __shared__ float Ws[I_][J_];   // 64 KB
    __shared__ float Xs[KT][I_];   // 16 KB

    const int t  = threadIdx.x;
    const int blk = blockIdx.x;                 // ((b*E + e)*(K/KT) + kt)
    const int kt = blk % (K_ / KT);
    const int be = blk / (K_ / KT);
    const int e  = be % E_;
    const int b  = be / E_;
    const int k0 = kt * KT;

    // ---- Stage W[e]: 4096 float4, 16 per thread (coalesced) ----
    const float4* Wg  = reinterpret_cast<const float4*>(W + (size_t)e * I_ * J_);
    float4*       WsV = reinterpret_cast<float4*>(&Ws[0][0]);
#pragma unroll
    for (int it = 0; it < 16; ++it)
        WsV[t + 256 * it] = Wg[t + 256 * it];

    // ---- Stage gathered X rows: 1024 float4, 4 per thread ----
    // 32 threads cooperate per row (128 floats = 32 float4), coalesced.
    const long ind_base = ((long)(b * E_ + e)) * K_ + k0;
    float4* XsV = reinterpret_cast<float4*>(&Xs[0][0]);
#pragma unroll
    for (int it = 0; it < 4; ++it) {
        const int s   = t + 256 * it;
        const int row = s >> 5;      // 0..31
        const int c4  = s & 31;      // float4 column
        const int idx = ind[ind_base + row];
        XsV[s] = reinterpret_cast<const float4*>(X + ((long)b * T_ + idx) * I_)[c4];
    }
    __syncthreads();

    // ---- Compute: thread micro-tile 4k x 4j ----
    const int jg = t & 31;   // j = jg*4
    const int kg = t >> 5;   // k = kg*4  (0..7)

    float acc[4][4];
#pragma unroll
    for (int a = 0; a < 4; ++a)
#pragma unroll
        for (int c = 0; c < 4; ++c) acc[a][c] = 0.f;

#pragma unroll 4
    for (int i = 0; i < I_; i += 4) {
        float xv[4][4], wv[4][4];
#pragma unroll
        for (int kk = 0; kk < 4; ++kk) {
            const float4 x4 = *reinterpret_cast<const float4*>(&Xs[kg * 4 + kk][i]);
            xv[kk][0] = x4.x; xv[kk][1] = x4.y; xv[kk][2] = x4.z; xv[kk][3] = x4.w;
        }
#pragma unroll
        for (int ii = 0; ii < 4; ++ii) {
            const float4 w4 = *reinterpret_cast<const float4*>(&Ws[i + ii][jg * 4]);
            wv[ii][0] = w4.x; wv[ii][1] = w4.y; wv[ii][2] = w4.z; wv[ii][3] = w4.w;
        }
#pragma unroll
        for (int kk = 0; kk < 4; ++kk)
#pragma unroll
            for (int ii = 0; ii < 4; ++ii)
#pragma unroll
                for (int jj = 0; jj < 4; ++jj)
                    acc[kk][jj] = fmaf(xv[kk][ii], wv[ii][jj], acc[kk][jj]);
    }

    // ---- Store: float4 per k-row, lanes cover consecutive j (coalesced) ----
    float* Yb = Y + ((size_t)be * K_ + k0) * J_;
#pragma unroll
    for (int kk = 0; kk < 4; ++kk) {
        float4 o;
        o.x = acc[kk][0]; o.y = acc[kk][1]; o.z = acc[kk][2]; o.w = acc[kk][3];
        *reinterpret_cast<float4*>(Yb + (size_t)(kg * 4 + kk) * J_ + jg * 4) = o;
    }
}

extern "C" void kernel_launch(void* const* d_in, const int* in_sizes, int n_in,
                              void* d_out, int out_size, void* d_ws, size_t ws_size,
                              hipStream_t stream) {
    (void)in_sizes; (void)n_in; (void)d_ws; (void)ws_size; (void)out_size;
    const float* X   = (const float*)d_in[0];
    const int*   ind = (const int*)d_in[1];
    const float* W   = (const float*)d_in[2];
    float*       Y   = (float*)d_out;

    const int grid = B_ * E_ * (K_ / KT);   // 4096 blocks
    hipLaunchKernelGGL(gather_gemm_f32, dim3(grid), dim3(256), 0, stream,
                       X, ind, W, Y);
}

// Round 2
// 32.077 us; speedup vs baseline: 2.1567x; 2.1567x over previous
//
#include <hip/hip_runtime.h>

// Y[b,e,k,j] = sum_i X[b, ind[b,e,k], i] * W[e,i,j]
// X:[B,T,I] f32, ind:[B,E,K] int32, W:[E,I,J] f32 -> Y:[B,E,K,J] f32
#define B_ 8
#define T_ 8192
#define I_ 128
#define E_ 16
#define J_ 128
#define K_ 1024
#define ROWS 64   // k-rows per block

typedef unsigned short u16;
typedef unsigned int   u32;
typedef __attribute__((ext_vector_type(8))) short s8v;   // 8 bf16 = 4 VGPRs
typedef __attribute__((ext_vector_type(4))) float f4v;   // MFMA accumulator

__device__ __forceinline__ u16 f2bf(float f) {
    union { float f; u32 u; } v; v.f = f;
    const u32 u = v.u;
    return (u16)((u + 0x7fffu + ((u >> 16) & 1u)) >> 16);  // RNE
}

// ---- Prepass: Wt[e][j][i] = bf16(W[e][i][j]) ----
__global__ void convert_wt(const float* __restrict__ W, u16* __restrict__ Wt) {
    const int t  = blockIdx.x * 256 + threadIdx.x;  // 32768 threads
    const int o8 = t * 8;                           // 8 outputs along i
    const int e  = o8 >> 14;
    const int r  = o8 & 16383;
    const int j  = r >> 7;
    const int i0 = r & 127;
    const float* Wp = W + e * (I_ * J_) + j;        // column j of W[e]
    s8v o;
#pragma unroll
    for (int u = 0; u < 8; ++u)
        o[u] = (short)f2bf(Wp[(i0 + u) * J_]);
    *reinterpret_cast<s8v*>(Wt + o8) = o;
}

// ---- Main: gather + bf16 MFMA GEMM ----
// LDS (both XOR-swizzled: physical_byte = logical_byte ^ ((row&7)<<4)):
//   WsT[j][i] 128x128 bf16 = 32KB,  Xs[r][i] 64x128 bf16 = 16KB  -> 48KB, 3 blk/CU
template<bool PRE>
__global__ __launch_bounds__(256, 3)
void gather_mfma(const float* __restrict__ X, const int* __restrict__ ind,
                 const void* __restrict__ Wsrc, float* __restrict__ Y) {
    __shared__ u16 WsT[I_ * J_];
    __shared__ u16 Xs[ROWS * I_];

    const int t    = threadIdx.x;
    const int wave = t >> 6;
    const int lane = t & 63;

    const int kt = blockIdx.x & 15;      // K_/ROWS = 16
    const int be = blockIdx.x >> 4;
    const int e  = be & (E_ - 1);
    const int b  = be >> 4;
    const int k0 = kt * ROWS;

    // ---- Stage WsT ----
    if (PRE) {
        // Wt is bf16 [j][i]: copy 16B chunks, swizzled dest.
        const s8v* Wg = reinterpret_cast<const s8v*>((const u16*)Wsrc + (size_t)e * (I_ * J_));
#pragma unroll
        for (int u = 0; u < 8; ++u) {
            const int c   = t + 256 * u;          // 16B chunk id, 0..2047
            const int row = c >> 4;               // j
            const s8v v = Wg[c];
            *reinterpret_cast<s8v*>((char*)WsT + ((c * 16) ^ ((row & 7) << 4))) = v;
        }
    } else {
        // Fallback: transpose+convert W[e] (f32 [i][j]) inline.
        const float* We = (const float*)Wsrc + (size_t)e * (I_ * J_);
#pragma unroll
        for (int u = 0; u < 16; ++u) {
            const int f4i = t + 256 * u;          // float4 id, 0..4095
            const int i   = f4i >> 5;
            const int j0  = (f4i & 31) * 4;
            const float4 w4 = reinterpret_cast<const float4*>(We)[f4i];
            const float ws[4] = {w4.x, w4.y, w4.z, w4.w};
#pragma unroll
            for (int q = 0; q < 4; ++q) {
                const int j = j0 + q;
                *(u16*)((char*)WsT + ((j * 256 + i * 2) ^ ((j & 7) << 4))) = f2bf(ws[q]);
            }
        }
    }

    // ---- Stage Xs: gather 64 rows, convert f32->bf16 ----
    {
        const int r   = t >> 2;                   // row 0..63
        const int q   = t & 3;                    // 32-elem quarter
        const int idx = ind[(size_t)be * K_ + k0 + r];
        const float4* Xr = reinterpret_cast<const float4*>(X + ((size_t)b * T_ + idx) * I_) + q * 8;
        const int sx = (r & 7) << 4;
        char* xrow = (char*)Xs + r * 256;
#pragma unroll
        for (int u = 0; u < 4; ++u) {
            const float4 a = Xr[2 * u], c = Xr[2 * u + 1];
            s8v o;
            o[0] = (short)f2bf(a.x); o[1] = (short)f2bf(a.y);
            o[2] = (short)f2bf(a.z); o[3] = (short)f2bf(a.w);
            o[4] = (short)f2bf(c.x); o[5] = (short)f2bf(c.y);
            o[6] = (short)f2bf(c.z); o[7] = (short)f2bf(c.w);
            *reinterpret_cast<s8v*>(xrow + ((q * 64 + u * 16) ^ sx)) = o;
        }
    }
    __syncthreads();

    // ---- Compute: wave = (row-half rh, j-half jh); 32 rows x 64 cols ----
    // Fragment k-index map c = 32s + 8*(lane>>4) + j applied identically to A
    // and B: correct for ANY true per-lane K order (A/B share the same f).
    const int rh  = wave >> 1;
    const int jh  = wave & 1;
    const int g   = lane >> 4;
    const int l15 = lane & 15;
    const int sx  = (lane & 7) << 4;   // == ((row&7)<<4) for both A-rows and B-rows

    f4v acc[2][4];
#pragma unroll
    for (int tr = 0; tr < 2; ++tr)
#pragma unroll
        for (int n = 0; n < 4; ++n)
#pragma unroll
            for (int r = 0; r < 4; ++r) acc[tr][n][r] = 0.f;

    const char* xb = (const char*)Xs  + (rh * 32 + l15) * 256;
    const char* wb = (const char*)WsT + (jh * 64 + l15) * 256;
#pragma unroll
    for (int s = 0; s < 4; ++s) {
        const int off = (s * 64 + g * 16) ^ sx;
        const s8v a0 = *reinterpret_cast<const s8v*>(xb + off);
        const s8v a1 = *reinterpret_cast<const s8v*>(xb + 16 * 256 + off);
#pragma unroll
        for (int n = 0; n < 4; ++n) {
            const s8v bf = *reinterpret_cast<const s8v*>(wb + n * 16 * 256 + off);
            acc[0][n] = __builtin_amdgcn_mfma_f32_16x16x32_bf16(a0, bf, acc[0][n], 0, 0, 0);
            acc[1][n] = __builtin_amdgcn_mfma_f32_16x16x32_bf16(a1, bf, acc[1][n], 0, 0, 0);
        }
    }

    // ---- Store (C/D: col = lane&15, row = 4*(lane>>4)+reg) ----
    float* Yb = Y + ((size_t)be * K_ + k0) * J_;
#pragma unroll
    for (int tr = 0; tr < 2; ++tr)
#pragma unroll
        for (int n = 0; n < 4; ++n) {
            const int col = jh * 64 + n * 16 + l15;
            const int row0 = rh * 32 + tr * 16 + g * 4;
#pragma unroll
            for (int r = 0; r < 4; ++r)
                Yb[(size_t)(row0 + r) * J_ + col] = acc[tr][n][r];
        }
}

extern "C" void kernel_launch(void* const* d_in, const int* in_sizes, int n_in,
                              void* d_out, int out_size, void* d_ws, size_t ws_size,
                              hipStream_t stream) {
    (void)in_sizes; (void)n_in; (void)out_size;
    const float* X   = (const float*)d_in[0];
    const int*   ind = (const int*)d_in[1];
    const float* W   = (const float*)d_in[2];
    float*       Y   = (float*)d_out;

    const size_t wt_bytes = (size_t)E_ * I_ * J_ * sizeof(u16);  // 512 KB
    const int grid = B_ * E_ * (K_ / ROWS);                       // 2048

    if (ws_size >= wt_bytes && d_ws != nullptr) {
        u16* Wt = (u16*)d_ws;
        hipLaunchKernelGGL(convert_wt, dim3(E_ * I_ * J_ / (256 * 8)), dim3(256), 0, stream, W, Wt);
        hipLaunchKernelGGL((gather_mfma<true>), dim3(grid), dim3(256), 0, stream,
                           X, ind, (const void*)Wt, Y);
    } else {
        hipLaunchKernelGGL((gather_mfma<false>), dim3(grid), dim3(256), 0, stream,
                           X, ind, (const void*)W, Y);
    }
}